// Round 5
// baseline (161.446 us; speedup 1.0000x reference)
//
#include <hip/hip_runtime.h>

// HydrophobicPairs: E[b,l] = h[seq[b,l]] * sum_k h[seq[b, j_idx[b,l,k]]] * g(r[b,l,k])
// g(r) = exp(-(r_c - r_peak)^2 / (2 sigma^2)) * (r < md - 1e-4)
// B=32, L=8192, K=64, NUM_AA=20.
//
// R5: R2-R4 all sat at ~47-51us with NO pipe >25% busy, independent of
// prefetch depth => stall is the serial per-iteration reduction chain:
// __shfl_xor -> ds_swizzle_b32 shares in-order lgkmcnt with the gathers,
// forcing 4 full LDS-queue drains per iteration per wave.
// Fix: DPP row_shr adds (pure VALU, no lgkmcnt): lane15 of each 16-lane
// row accumulates the row sum. Everything else identical to R4.

#define BB 32
#define LL 8192
#define KK 64
#define TPB 512
#define RPB 256   // rows per block
#define DEPTH 2   // prefetch depth (iterations in flight)

__global__ __launch_bounds__(256) void _hp_hall_kernel(
    const int* __restrict__ seq, const float* __restrict__ h,
    float* __restrict__ h_all)
{
    const int idx = blockIdx.x * 256 + threadIdx.x;      // int4 index, 65536 total
    const int4 s = ((const int4*)seq)[idx];
    ((float4*)h_all)[idx] = make_float4(h[s.x], h[s.y], h[s.z], h[s.w]);
}

// Sum across each 16-lane row via DPP row_shr (VALU-only, no LDS pipe).
// bound_ctrl=1 zero-fills shifted-in lanes. Result lands in lane 15 of each row.
__device__ __forceinline__ float row16_sum(float x) {
    x += __int_as_float(__builtin_amdgcn_mov_dpp(__float_as_int(x), 0x111, 0xF, 0xF, true)); // row_shr:1
    x += __int_as_float(__builtin_amdgcn_mov_dpp(__float_as_int(x), 0x112, 0xF, 0xF, true)); // row_shr:2
    x += __int_as_float(__builtin_amdgcn_mov_dpp(__float_as_int(x), 0x114, 0xF, 0xF, true)); // row_shr:4
    x += __int_as_float(__builtin_amdgcn_mov_dpp(__float_as_int(x), 0x118, 0xF, 0xF, true)); // row_shr:8
    return x;
}

__global__ __launch_bounds__(TPB) void _HydrophobicPairs_58256936403302_kernel(
    const float* __restrict__ r,          // [B,L,K]
    const int*   __restrict__ j_idx,      // [B,L,K]
    const float* __restrict__ h_all,      // [B,L] precomputed h[seq]
    const float* __restrict__ r_half_raw, // [1]
    const float* __restrict__ tau_hp_raw, // [1]
    const int*   __restrict__ max_dist,   // [1]
    float*       __restrict__ out)        // [B,L]
{
    __shared__ float h_row[LL];           // 32 KB
    const int tid   = threadIdx.x;
    const int b     = blockIdx.x >> 5;    // 32 chunks per b
    const int chunk = blockIdx.x & 31;
    const int lbase = chunk * RPB;

    // Stage h_all[b, :] -> LDS (pure coalesced copy, no gather).
    const float4* hsrc = (const float4*)(h_all + b * LL);
    #pragma unroll
    for (int i = 0; i < 4; ++i) {
        const int e4 = i * TPB + tid;     // 0..2047 float4s
        ((float4*)h_row)[e4] = hsrc[e4];
    }

    // Runtime scalars (broadcast, cached).
    const float md     = (float)max_dist[0];
    const float r_peak = log1pf(expf(r_half_raw[0]));            // softplus
    const float sigma  = log1pf(expf(tau_hp_raw[0])) + 0.1f;
    const float nscale = -1.44269504f / (2.0f * sigma * sigma);  // -log2e/(2s^2)
    const float c1     = -2.0f * nscale * r_peak;
    const float c0     = nscale * r_peak * r_peak;
    const float vthr   = md - 1e-4f;

    // 16 lanes/row: each global_load_dwordx4 covers a contiguous 1 KB segment.
    const int lane = tid & 15;
    const int rgrp = tid >> 4;            // 0..31 rows per iteration
    const long base0 = ((long)(b * LL + lbase + rgrp)) * KK + lane * 4;

    // Fill the pipeline (global loads don't depend on LDS -> before barrier).
    float4 rbuf[DEPTH]; int4 jbuf[DEPTH];
    #pragma unroll
    for (int p = 0; p < DEPTH; ++p) {
        const long nb = base0 + (long)p * (32 * KK);
        rbuf[p] = *(const float4*)(r + nb);
        jbuf[p] = *(const int4*)(j_idx + nb);
    }

    __syncthreads();

    #pragma unroll
    for (int it = 0; it < 8; ++it) {
        const int slot = it & (DEPTH - 1);
        const float4 rc = rbuf[slot];
        const int4   jc = jbuf[slot];
        if (it + DEPTH < 8) {             // refill this slot DEPTH iters ahead
            const long nb = base0 + (long)(it + DEPTH) * (32 * KK);
            rbuf[slot] = *(const float4*)(r + nb);
            jbuf[slot] = *(const int4*)(j_idx + nb);
        }

        float acc = 0.0f;
        #pragma unroll
        for (int u = 0; u < 4; ++u) {
            const float rv = (&rc.x)[u];
            const unsigned j = (unsigned)(&jc.x)[u] & (LL - 1);
            const float hj = h_row[j];                        // LDS gather
            // exp(-(rv-r_peak)^2/(2s^2)) as exp2(nscale*rv^2 + c1*rv + c0):
            const float uexp = fmaf(rv, fmaf(nscale, rv, c1), c0);
            float g = exp2f(uexp);                            // v_exp_f32
            g = (rv < vthr) ? g : 0.0f;                       // validity mask
            acc = fmaf(hj, g, acc);
        }

        // Reduce across the 16-lane row group: DPP tree, sum lands in lane 15.
        acc = row16_sum(acc);

        if (lane == 15) {
            const int l_loc = lbase + it * 32 + rgrp;
            out[b * LL + l_loc] = h_row[l_loc] * acc;
        }
    }
}

extern "C" void kernel_launch(void* const* d_in, const int* in_sizes, int n_in,
                              void* d_out, int out_size, void* d_ws, size_t ws_size,
                              hipStream_t stream) {
    const int*   seq        = (const int*)d_in[0];
    const float* r          = (const float*)d_in[1];
    const int*   j_idx      = (const int*)d_in[2];
    const float* h          = (const float*)d_in[3];
    const float* r_half_raw = (const float*)d_in[4];
    const float* tau_hp_raw = (const float*)d_in[5];
    const int*   max_dist   = (const int*)d_in[6];
    float*       out        = (float*)d_out;
    float*       h_all      = (float*)d_ws;              // 1 MB scratch

    // K1: h_all[b,l] = h[seq[b,l]]  (65536 int4 elems)
    _hp_hall_kernel<<<dim3(256), dim3(256), 0, stream>>>(seq, h, h_all);

    // K2: main. 1024 blocks x 512 threads, 4 blocks/CU.
    _HydrophobicPairs_58256936403302_kernel<<<dim3(BB * (LL / RPB)), dim3(TPB), 0, stream>>>(
        r, j_idx, h_all, r_half_raw, tau_hp_raw, max_dist, out);
}

// Round 6
// 160.859 us; speedup vs baseline: 1.0036x; 1.0036x over previous
//
#include <hip/hip_runtime.h>

// HydrophobicPairs: E[b,l] = h[seq[b,l]] * sum_k h[seq[b, j_idx[b,l,k]]] * g(r[b,l,k])
// g(r) = exp(-(r_c - r_peak)^2 / (2 sigma^2)) * (r < md - 1e-4)
// B=32, L=8192, K=64, NUM_AA=20.
//
// R6: R2-R5 invariant at ~47us with all pipes <25% busy. Hypothesis: per-wave
// memory-level parallelism (waves stall on gather/reduce before issuing next
// stream loads). DEPTH=4 keeps 8 dwordx4 in flight per wave. K1 fused away:
// h_row staged by gathering the 80B h table directly from global (L1-hot),
// one barrier, single kernel launch.

#define BB 32
#define LL 8192
#define KK 64
#define TPB 512
#define RPB 256   // rows per block
#define DEPTH 4   // prefetch depth (iterations in flight; 2 loads each)

// Sum across each 16-lane row via DPP row_shr (VALU-only, no lgkmcnt).
// bound_ctrl=1 zero-fills shifted-in lanes. Result lands in lane 15 of each row.
__device__ __forceinline__ float row16_sum(float x) {
    x += __int_as_float(__builtin_amdgcn_mov_dpp(__float_as_int(x), 0x111, 0xF, 0xF, true)); // row_shr:1
    x += __int_as_float(__builtin_amdgcn_mov_dpp(__float_as_int(x), 0x112, 0xF, 0xF, true)); // row_shr:2
    x += __int_as_float(__builtin_amdgcn_mov_dpp(__float_as_int(x), 0x114, 0xF, 0xF, true)); // row_shr:4
    x += __int_as_float(__builtin_amdgcn_mov_dpp(__float_as_int(x), 0x118, 0xF, 0xF, true)); // row_shr:8
    return x;
}

__global__ __launch_bounds__(TPB) void _HydrophobicPairs_58256936403302_kernel(
    const int*   __restrict__ seq,        // [B,L]
    const float* __restrict__ r,          // [B,L,K]
    const int*   __restrict__ j_idx,      // [B,L,K]
    const float* __restrict__ h,          // [20]
    const float* __restrict__ r_half_raw, // [1]
    const float* __restrict__ tau_hp_raw, // [1]
    const int*   __restrict__ max_dist,   // [1]
    float*       __restrict__ out)        // [B,L]
{
    __shared__ float h_row[LL];           // 32 KB
    const int tid   = threadIdx.x;
    const int b     = blockIdx.x >> 5;    // 32 chunks per b
    const int chunk = blockIdx.x & 31;
    const int lbase = chunk * RPB;

    // Stage h[seq[b, :]] -> LDS. h is 80 B (L1-hot broadcast-ish gather);
    // seq read as int4, fully coalesced. No h_tab barrier, no separate kernel.
    const int4* seq4 = (const int4*)(seq + b * LL);
    #pragma unroll
    for (int i = 0; i < 4; ++i) {
        const int e4 = i * TPB + tid;     // 0..2047 int4s
        const int4 s = seq4[e4];
        ((float4*)h_row)[e4] = make_float4(h[s.x], h[s.y], h[s.z], h[s.w]);
    }

    // Runtime scalars (broadcast, cached).
    const float md     = (float)max_dist[0];
    const float r_peak = log1pf(expf(r_half_raw[0]));            // softplus
    const float sigma  = log1pf(expf(tau_hp_raw[0])) + 0.1f;
    const float nscale = -1.44269504f / (2.0f * sigma * sigma);  // -log2e/(2s^2)
    const float c1     = -2.0f * nscale * r_peak;
    const float c0     = nscale * r_peak * r_peak;
    const float vthr   = md - 1e-4f;

    // 16 lanes/row: each global_load_dwordx4 covers a contiguous 1 KB segment.
    const int lane = tid & 15;
    const int rgrp = tid >> 4;            // 0..31 rows per iteration
    const long base0 = ((long)(b * LL + lbase + rgrp)) * KK + lane * 4;

    // Fill the pipeline: 8 dwordx4 loads in flight before the barrier.
    float4 rbuf[DEPTH]; int4 jbuf[DEPTH];
    #pragma unroll
    for (int p = 0; p < DEPTH; ++p) {
        const long nb = base0 + (long)p * (32 * KK);
        rbuf[p] = *(const float4*)(r + nb);
        jbuf[p] = *(const int4*)(j_idx + nb);
    }

    __syncthreads();

    #pragma unroll
    for (int it = 0; it < 8; ++it) {
        const int slot = it & (DEPTH - 1);
        const float4 rc = rbuf[slot];
        const int4   jc = jbuf[slot];
        if (it + DEPTH < 8) {             // refill this slot DEPTH iters ahead
            const long nb = base0 + (long)(it + DEPTH) * (32 * KK);
            rbuf[slot] = *(const float4*)(r + nb);
            jbuf[slot] = *(const int4*)(j_idx + nb);
        }

        float acc = 0.0f;
        #pragma unroll
        for (int u = 0; u < 4; ++u) {
            const float rv = (&rc.x)[u];
            const unsigned j = (unsigned)(&jc.x)[u] & (LL - 1);
            const float hj = h_row[j];                        // LDS gather
            // exp(-(rv-r_peak)^2/(2s^2)) as exp2(nscale*rv^2 + c1*rv + c0):
            const float uexp = fmaf(rv, fmaf(nscale, rv, c1), c0);
            float g = exp2f(uexp);                            // v_exp_f32
            g = (rv < vthr) ? g : 0.0f;                       // validity mask
            acc = fmaf(hj, g, acc);
        }

        // Reduce across the 16-lane row group: DPP tree, sum lands in lane 15.
        acc = row16_sum(acc);

        if (lane == 15) {
            const int l_loc = lbase + it * 32 + rgrp;
            out[b * LL + l_loc] = h_row[l_loc] * acc;
        }
    }
}

extern "C" void kernel_launch(void* const* d_in, const int* in_sizes, int n_in,
                              void* d_out, int out_size, void* d_ws, size_t ws_size,
                              hipStream_t stream) {
    const int*   seq        = (const int*)d_in[0];
    const float* r          = (const float*)d_in[1];
    const int*   j_idx      = (const int*)d_in[2];
    const float* h          = (const float*)d_in[3];
    const float* r_half_raw = (const float*)d_in[4];
    const float* tau_hp_raw = (const float*)d_in[5];
    const int*   max_dist   = (const int*)d_in[6];
    float*       out        = (float*)d_out;

    // Single fused kernel: 1024 blocks x 512 threads, 4 blocks/CU.
    _HydrophobicPairs_58256936403302_kernel<<<dim3(BB * (LL / RPB)), dim3(TPB), 0, stream>>>(
        seq, r, j_idx, h, r_half_raw, tau_hp_raw, max_dist, out);
}

// Round 7
// 160.822 us; speedup vs baseline: 1.0039x; 1.0002x over previous
//
#include <hip/hip_runtime.h>

// HydrophobicPairs: E[b,l] = h[seq[b,l]] * sum_k h[seq[b, j_idx[b,l,k]]] * g(r[b,l,k])
// g(r) = exp(-(r_c - r_peak)^2 / (2 sigma^2)) * (r < md - 1e-4)
// B=32, L=8192, K=64, NUM_AA=20.
//
// R7: R2-R6 invariant at 45-51us, all pipes <25%. Model: per-CU read-stream
// ceiling (~5 B/cyc/CU, L1 outstanding-miss limited) — delivered 2.8 TB/s of
// the ~3.2 TB/s read-only ceiling. Final discriminator: 32 waves/CU
// (TPB=1024, 2 blocks/CU) + halved seq-staging redundancy. If invariant,
// the kernel is at the streaming roofline (128 MB mandatory input reads).

#define BB 32
#define LL 8192
#define KK 64
#define TPB 1024
#define RPB 512   // rows per block -> 512 blocks total, 2/CU
#define DEPTH 4   // prefetch depth (iterations in flight; 2 loads each)

// Sum across each 16-lane row via DPP row_shr (VALU-only, no lgkmcnt).
// bound_ctrl=1 zero-fills shifted-in lanes. Result lands in lane 15 of each row.
__device__ __forceinline__ float row16_sum(float x) {
    x += __int_as_float(__builtin_amdgcn_mov_dpp(__float_as_int(x), 0x111, 0xF, 0xF, true)); // row_shr:1
    x += __int_as_float(__builtin_amdgcn_mov_dpp(__float_as_int(x), 0x112, 0xF, 0xF, true)); // row_shr:2
    x += __int_as_float(__builtin_amdgcn_mov_dpp(__float_as_int(x), 0x114, 0xF, 0xF, true)); // row_shr:4
    x += __int_as_float(__builtin_amdgcn_mov_dpp(__float_as_int(x), 0x118, 0xF, 0xF, true)); // row_shr:8
    return x;
}

__global__ __launch_bounds__(TPB) void _HydrophobicPairs_58256936403302_kernel(
    const int*   __restrict__ seq,        // [B,L]
    const float* __restrict__ r,          // [B,L,K]
    const int*   __restrict__ j_idx,      // [B,L,K]
    const float* __restrict__ h,          // [20]
    const float* __restrict__ r_half_raw, // [1]
    const float* __restrict__ tau_hp_raw, // [1]
    const int*   __restrict__ max_dist,   // [1]
    float*       __restrict__ out)        // [B,L]
{
    __shared__ float h_row[LL];           // 32 KB
    const int tid   = threadIdx.x;
    const int b     = blockIdx.x >> 4;    // 16 chunks per b
    const int chunk = blockIdx.x & 15;
    const int lbase = chunk * RPB;

    // Stage h[seq[b, :]] -> LDS. h is 80 B (L1-hot gather); seq read as int4.
    const int4* seq4 = (const int4*)(seq + b * LL);
    #pragma unroll
    for (int i = 0; i < 2; ++i) {
        const int e4 = i * TPB + tid;     // 0..2047 int4s
        const int4 s = seq4[e4];
        ((float4*)h_row)[e4] = make_float4(h[s.x], h[s.y], h[s.z], h[s.w]);
    }

    // Runtime scalars (broadcast, cached).
    const float md     = (float)max_dist[0];
    const float r_peak = log1pf(expf(r_half_raw[0]));            // softplus
    const float sigma  = log1pf(expf(tau_hp_raw[0])) + 0.1f;
    const float nscale = -1.44269504f / (2.0f * sigma * sigma);  // -log2e/(2s^2)
    const float c1     = -2.0f * nscale * r_peak;
    const float c0     = nscale * r_peak * r_peak;
    const float vthr   = md - 1e-4f;

    // 16 lanes/row: each global_load_dwordx4 covers a contiguous 1 KB segment.
    const int lane = tid & 15;
    const int rgrp = tid >> 4;            // 0..63 rows per iteration
    const long base0 = ((long)(b * LL + lbase + rgrp)) * KK + lane * 4;

    // Fill the pipeline: 8 dwordx4 loads in flight before the barrier.
    float4 rbuf[DEPTH]; int4 jbuf[DEPTH];
    #pragma unroll
    for (int p = 0; p < DEPTH; ++p) {
        const long nb = base0 + (long)p * (64 * KK);
        rbuf[p] = *(const float4*)(r + nb);
        jbuf[p] = *(const int4*)(j_idx + nb);
    }

    __syncthreads();

    #pragma unroll
    for (int it = 0; it < 8; ++it) {      // 8 iters x 64 rows = 512 rows
        const int slot = it & (DEPTH - 1);
        const float4 rc = rbuf[slot];
        const int4   jc = jbuf[slot];
        if (it + DEPTH < 8) {             // refill this slot DEPTH iters ahead
            const long nb = base0 + (long)(it + DEPTH) * (64 * KK);
            rbuf[slot] = *(const float4*)(r + nb);
            jbuf[slot] = *(const int4*)(j_idx + nb);
        }

        float acc = 0.0f;
        #pragma unroll
        for (int u = 0; u < 4; ++u) {
            const float rv = (&rc.x)[u];
            const unsigned j = (unsigned)(&jc.x)[u] & (LL - 1);
            const float hj = h_row[j];                        // LDS gather
            // exp(-(rv-r_peak)^2/(2s^2)) as exp2(nscale*rv^2 + c1*rv + c0):
            const float uexp = fmaf(rv, fmaf(nscale, rv, c1), c0);
            float g = exp2f(uexp);                            // v_exp_f32
            g = (rv < vthr) ? g : 0.0f;                       // validity mask
            acc = fmaf(hj, g, acc);
        }

        // Reduce across the 16-lane row group: DPP tree, sum lands in lane 15.
        acc = row16_sum(acc);

        if (lane == 15) {
            const int l_loc = lbase + it * 64 + rgrp;
            out[b * LL + l_loc] = h_row[l_loc] * acc;
        }
    }
}

extern "C" void kernel_launch(void* const* d_in, const int* in_sizes, int n_in,
                              void* d_out, int out_size, void* d_ws, size_t ws_size,
                              hipStream_t stream) {
    const int*   seq        = (const int*)d_in[0];
    const float* r          = (const float*)d_in[1];
    const int*   j_idx      = (const int*)d_in[2];
    const float* h          = (const float*)d_in[3];
    const float* r_half_raw = (const float*)d_in[4];
    const float* tau_hp_raw = (const float*)d_in[5];
    const int*   max_dist   = (const int*)d_in[6];
    float*       out        = (float*)d_out;

    // 512 blocks x 1024 threads: 2 blocks/CU, 32 waves/CU.
    _HydrophobicPairs_58256936403302_kernel<<<dim3(BB * (LL / RPB)), dim3(TPB), 0, stream>>>(
        seq, r, j_idx, h, r_half_raw, tau_hp_raw, max_dist, out);
}

// Round 8
// 158.685 us; speedup vs baseline: 1.0174x; 1.0135x over previous
//
#include <hip/hip_runtime.h>

// HydrophobicPairs: E[b,l] = h[seq[b,l]] * sum_k h[seq[b, j_idx[b,l,k]]] * g(r[b,l,k])
// g(r) = exp(-(r_c - r_peak)^2 / (2 sigma^2)) * (r < md - 1e-4)
// B=32, L=8192, K=64, NUM_AA=20.
//
// R8: R2-R7 pinned at 45-51us, all pipes <25%, L3-resident replays equally
// slow => CU-ingress limit on the VGPR-return load path (~4.4 B/cyc/CU in
// flight; VGPR_Count 24-32 shows the compiler collapsed every source-level
// prefetch). Fix: stream r/j via __builtin_amdgcn_global_load_lds (async DMA,
// own queue, no VGPR return — m97 sustained ~21 B/cyc/CU on this path).
// Per-wave double-buffered 1KB+1KB chunks, explicit s_waitcnt vmcnt(N)
// (in-order retirement => exact counts), no K-loop barrier.

#define BB 32
#define LL 8192
#define KK 64
#define TPB 512
#define RPB 512          // rows per block -> 512 blocks, 2/CU
#define NWAVE 8
#define NCHUNK 16        // 16 chunks x 4 rows = 64 rows per wave

__device__ __forceinline__ void dma16(const void* g, void* l) {
    __builtin_amdgcn_global_load_lds(
        (const __attribute__((address_space(1))) void*)g,
        (__attribute__((address_space(3))) void*)l, 16, 0, 0);
}

// Sum across each 16-lane row via DPP row_shr (VALU-only). bound_ctrl=1
// zero-fills. Result lands in lane 15 of each 16-lane group.
__device__ __forceinline__ float row16_sum(float x) {
    x += __int_as_float(__builtin_amdgcn_mov_dpp(__float_as_int(x), 0x111, 0xF, 0xF, true)); // row_shr:1
    x += __int_as_float(__builtin_amdgcn_mov_dpp(__float_as_int(x), 0x112, 0xF, 0xF, true)); // row_shr:2
    x += __int_as_float(__builtin_amdgcn_mov_dpp(__float_as_int(x), 0x114, 0xF, 0xF, true)); // row_shr:4
    x += __int_as_float(__builtin_amdgcn_mov_dpp(__float_as_int(x), 0x118, 0xF, 0xF, true)); // row_shr:8
    return x;
}

__global__ __launch_bounds__(TPB) void _HydrophobicPairs_58256936403302_kernel(
    const int*   __restrict__ seq,        // [B,L]
    const float* __restrict__ r,          // [B,L,K]
    const int*   __restrict__ j_idx,      // [B,L,K]
    const float* __restrict__ h,          // [20]
    const float* __restrict__ r_half_raw, // [1]
    const float* __restrict__ tau_hp_raw, // [1]
    const int*   __restrict__ max_dist,   // [1]
    float*       __restrict__ out)        // [B,L]
{
    __shared__ float h_row[LL];                          // 32 KB
    __shared__ __align__(16) char sbuf[NWAVE][2][2048];  // 32 KB: [wave][slot][r:0..1K | j:1K..2K]

    const int tid  = threadIdx.x;
    const int wave = tid >> 6;
    const int lane = tid & 63;
    const int b     = blockIdx.x >> 4;    // 16 chunks of 512 rows per b
    const int lbase = (blockIdx.x & 15) * RPB;

    // Stage h[seq[b, :]] -> LDS (coalesced int4 reads; h is 80 B, L1-hot).
    const int4* seq4 = (const int4*)(seq + b * LL);
    #pragma unroll
    for (int i = 0; i < 4; ++i) {
        const int e4 = i * TPB + tid;     // 0..2047 int4s
        const int4 s = seq4[e4];
        ((float4*)h_row)[e4] = make_float4(h[s.x], h[s.y], h[s.z], h[s.w]);
    }

    // Runtime scalars (broadcast, cached).
    const float md     = (float)max_dist[0];
    const float r_peak = log1pf(expf(r_half_raw[0]));            // softplus
    const float sigma  = log1pf(expf(tau_hp_raw[0])) + 0.1f;
    const float nscale = -1.44269504f / (2.0f * sigma * sigma);  // -log2e/(2s^2)
    const float c1     = -2.0f * nscale * r_peak;
    const float c0     = nscale * r_peak * r_peak;
    const float vthr   = md - 1e-4f;

    __syncthreads();                      // h_row visible to all waves

    // Per-wave stream: 64 rows starting at l0; chunk = 4 rows = 1 KB each of r/j.
    const int l0 = lbase + wave * 64;
    const char* rg = (const char*)(r     + (long)(b * LL + l0) * KK) + lane * 16;
    const char* jg = (const char*)(j_idx + (long)(b * LL + l0) * KK) + lane * 16;

    // Prologue: DMA chunks 0 and 1 (4 vmem insts in flight).
    dma16(rg + 0 * 1024, &sbuf[wave][0][0]);
    dma16(jg + 0 * 1024, &sbuf[wave][0][1024]);
    dma16(rg + 1 * 1024, &sbuf[wave][1][0]);
    dma16(jg + 1 * 1024, &sbuf[wave][1][1024]);

    const int myrow = lane >> 4;          // 0..3 (row within chunk)
    const int klane = lane & 15;

    #pragma unroll
    for (int c = 0; c < NCHUNK; ++c) {
        // In-order vmem retirement: wait until chunk c's DMA-j has landed.
        // newer-than-dma_j(c): c=0 -> {r1,j1}=2; c=1 -> {r2,j2,st0}=3;
        // 2<=c<=14 -> {st(c-2),r(c+1),j(c+1),st(c-1)}=4; c=15 -> {st13,st14}=2.
        if      (c == 0)          asm volatile("s_waitcnt vmcnt(2)" ::: "memory");
        else if (c == 1)          asm volatile("s_waitcnt vmcnt(3)" ::: "memory");
        else if (c == NCHUNK - 1) asm volatile("s_waitcnt vmcnt(2)" ::: "memory");
        else                      asm volatile("s_waitcnt vmcnt(4)" ::: "memory");

        const int slot = c & 1;
        const float4 rc = *(const float4*)(&sbuf[wave][slot][lane * 16]);
        const int4   jc = *(const int4*)(&sbuf[wave][slot][1024 + lane * 16]);
        // Data must be in VGPRs before the refill DMA overwrites this slot.
        asm volatile("s_waitcnt lgkmcnt(0)" ::: "memory");

        if (c + 2 < NCHUNK) {             // refill this slot with chunk c+2
            dma16(rg + (c + 2) * 1024, &sbuf[wave][slot][0]);
            dma16(jg + (c + 2) * 1024, &sbuf[wave][slot][1024]);
        }

        float acc = 0.0f;
        #pragma unroll
        for (int u = 0; u < 4; ++u) {
            const float rv = (&rc.x)[u];
            const unsigned j = (unsigned)(&jc.x)[u] & (LL - 1);
            const float hj = h_row[j];                        // LDS gather
            const float uexp = fmaf(rv, fmaf(nscale, rv, c1), c0);
            float g = exp2f(uexp);                            // v_exp_f32
            g = (rv < vthr) ? g : 0.0f;                       // validity mask
            acc = fmaf(hj, g, acc);
        }

        acc = row16_sum(acc);             // sum over the 16 k-lanes of this row

        if (klane == 15) {
            const int lrow = l0 + c * 4 + myrow;
            out[b * LL + lrow] = h_row[lrow] * acc;
        }
    }
}

extern "C" void kernel_launch(void* const* d_in, const int* in_sizes, int n_in,
                              void* d_out, int out_size, void* d_ws, size_t ws_size,
                              hipStream_t stream) {
    const int*   seq        = (const int*)d_in[0];
    const float* r          = (const float*)d_in[1];
    const int*   j_idx      = (const int*)d_in[2];
    const float* h          = (const float*)d_in[3];
    const float* r_half_raw = (const float*)d_in[4];
    const float* tau_hp_raw = (const float*)d_in[5];
    const int*   max_dist   = (const int*)d_in[6];
    float*       out        = (float*)d_out;

    // 512 blocks x 512 threads: 2 blocks/CU (64 KB LDS each), 16 waves/CU.
    _HydrophobicPairs_58256936403302_kernel<<<dim3(BB * (LL / RPB)), dim3(TPB), 0, stream>>>(
        seq, r, j_idx, h, r_half_raw, tau_hp_raw, max_dist, out);
}